// Round 10
// baseline (509.003 us; speedup 1.0000x reference)
//
#include <hip/hip_runtime.h>

typedef __attribute__((ext_vector_type(8))) _Float16 half8;
typedef __attribute__((ext_vector_type(4))) _Float16 half4;
typedef __attribute__((ext_vector_type(4))) float f32x4;

#define SEQ 2048
#define DMODEL 1024
#define NHEAD 16
#define HEADD 64
#define NBH 32          // B * NHEAD
#define LUTW 4096

__device__ __forceinline__ void nt_store_f4(float* p, f32x4 v) {
    __builtin_nontemporal_store(v, (f32x4*)p);
}

// raw barrier: orders LDS only; global loads/stores stay in flight across it
#define LDS_BAR() do {                                   \
    __builtin_amdgcn_sched_barrier(0);                   \
    asm volatile("s_waitcnt lgkmcnt(0)" ::: "memory");   \
    __builtin_amdgcn_sched_barrier(0);                   \
    __builtin_amdgcn_s_barrier();                        \
    __builtin_amdgcn_sched_barrier(0);                   \
} while (0)

// ---------------- T5 relative position bucket ----------------
__device__ __forceinline__ int rel_bucket(int rel) {
    int ret = (rel > 0) ? 16 : 0;
    int rp = rel < 0 ? -rel : rel;
    if (rp < 8) return ret + rp;
    float x = logf((float)rp * 0.125f) / 2.7725887f * 8.0f;
    int v = 8 + (int)x;
    v = v < 15 ? v : 15;
    return ret + v;
}

// ---------------- prep: all casts + bias LUT in one launch ----------------
__global__ __launch_bounds__(256) void prep_kernel(const float* __restrict__ hs,
                                                   const float* __restrict__ Wq,
                                                   const float* __restrict__ Wk,
                                                   const float* __restrict__ Wv,
                                                   const float* __restrict__ Wo,
                                                   const float* __restrict__ rel_bias,
                                                   _Float16* __restrict__ Xh,
                                                   _Float16* __restrict__ Wqh,
                                                   _Float16* __restrict__ Wkh,
                                                   _Float16* __restrict__ Wvh,
                                                   _Float16* __restrict__ Woh,
                                                   float* __restrict__ lut) {
    int bid = blockIdx.x;
    if (bid < 4096) {
        const float* in;
        _Float16* out;
        int base;
        if (bid < 2048)      { in = hs; out = Xh;  base = bid; }
        else if (bid < 2560) { in = Wq; out = Wqh; base = bid - 2048; }
        else if (bid < 3072) { in = Wk; out = Wkh; base = bid - 2560; }
        else if (bid < 3584) { in = Wv; out = Wvh; base = bid - 3072; }
        else                 { in = Wo; out = Woh; base = bid - 3584; }
        int i = (base * 256 + threadIdx.x) * 8;
        f32x4 a = *(const f32x4*)(in + i);
        f32x4 b = *(const f32x4*)(in + i + 4);
        half8 r;
        r[0] = (_Float16)a[0]; r[1] = (_Float16)a[1];
        r[2] = (_Float16)a[2]; r[3] = (_Float16)a[3];
        r[4] = (_Float16)b[0]; r[5] = (_Float16)b[1];
        r[6] = (_Float16)b[2]; r[7] = (_Float16)b[3];
        *(half8*)(out + i) = r;
    } else {
        int i = (bid - 4096) * 256 + threadIdx.x;   // 16 * 4096
        int h = i >> 12;
        int idx = i & (LUTW - 1);
        int rel = idx - 2047;
        int b = rel_bucket(rel);
        lut[i] = rel_bias[b * NHEAD + h];
    }
}

// ---------------- LDS-staged 128x128 GEMM body: C = A[M,K] * B[N=1024,K]^T ----------------
// mode 0: C fp16 (ptr C16) ; mode 1: Vt transpose (ptr C16) ; mode 2: C fp32 (ptr C32)
__device__ __forceinline__ void gemm128_body(const _Float16* __restrict__ A,
                                             const _Float16* __restrict__ B,
                                             _Float16* __restrict__ C16,
                                             float* __restrict__ C32,
                                             int K, int row0, int col0, int mode) {
    __shared__ _Float16 As[128][34];
    __shared__ _Float16 Bs[128][34];
    int tid = threadIdx.x;
    int l = tid & 63, w = tid >> 6;
    int ar = l & 15, ak = (l >> 4) * 8;
    int srow = w * 32 + (l >> 2);       // staging row within tile
    int scol = (l & 3) * 8;             // staging col (halves)
    const _Float16* ga0 = A + (size_t)(row0 + srow) * K + scol;
    const _Float16* ga1 = A + (size_t)(row0 + srow + 16) * K + scol;
    const _Float16* gb0 = B + (size_t)(col0 + srow) * K + scol;
    const _Float16* gb1 = B + (size_t)(col0 + srow + 16) * K + scol;
    int mrow = (w >> 1) * 64;           // wave's C quadrant
    int ncol = (w & 1) * 64;

    half8 a0 = *(const half8*)ga0;
    half8 a1 = *(const half8*)ga1;
    half8 b0 = *(const half8*)gb0;
    half8 b1 = *(const half8*)gb1;

    f32x4 acc[4][4] = {};
    for (int k0 = 0; k0 < K; k0 += 32) {
        *(half8*)&As[srow][scol] = a0;
        *(half8*)&As[srow + 16][scol] = a1;
        *(half8*)&Bs[srow][scol] = b0;
        *(half8*)&Bs[srow + 16][scol] = b1;
        LDS_BAR();
        if (k0 + 32 < K) {   // prefetch next k-step; spans barriers
            a0 = *(const half8*)(ga0 + k0 + 32);
            a1 = *(const half8*)(ga1 + k0 + 32);
            b0 = *(const half8*)(gb0 + k0 + 32);
            b1 = *(const half8*)(gb1 + k0 + 32);
        }
        half8 af[4], bf[4];
#pragma unroll
        for (int mi = 0; mi < 4; mi++)
            af[mi] = *(const half8*)&As[mrow + mi * 16 + ar][ak];
#pragma unroll
        for (int ni = 0; ni < 4; ni++)
            bf[ni] = *(const half8*)&Bs[ncol + ni * 16 + ar][ak];
#pragma unroll
        for (int mi = 0; mi < 4; mi++)
#pragma unroll
            for (int ni = 0; ni < 4; ni++)
                acc[mi][ni] = __builtin_amdgcn_mfma_f32_16x16x32_f16(af[mi], bf[ni], acc[mi][ni], 0, 0, 0);
        LDS_BAR();
    }
    // C indexing: include the wave quadrant (this was the round-9 bug)
    int r0 = row0 + mrow;
    int c0 = col0 + ncol;
    int cr = (l >> 4) * 4, cc = l & 15;
    if (mode == 0) {
#pragma unroll
        for (int mi = 0; mi < 4; mi++)
#pragma unroll
            for (int ni = 0; ni < 4; ni++) {
                int c = c0 + ni * 16 + cc;
#pragma unroll
                for (int j = 0; j < 4; j++)
                    C16[(size_t)(r0 + mi * 16 + cr + j) * DMODEL + c] = (_Float16)acc[mi][ni][j];
            }
    } else if (mode == 1) {
#pragma unroll
        for (int mi = 0; mi < 4; mi++)
#pragma unroll
            for (int ni = 0; ni < 4; ni++) {
                int c = c0 + ni * 16 + cc;
                int h = c >> 6, hd = c & 63;
                int r = r0 + mi * 16 + cr;
                int b = r >> 11, s0 = r & 2047;
                half4 pk;
#pragma unroll
                for (int j = 0; j < 4; j++) pk[j] = (_Float16)acc[mi][ni][j];
                *(half4*)(C16 + (size_t)((b * NHEAD + h) * HEADD + hd) * SEQ + s0) = pk;
            }
    } else {
#pragma unroll
        for (int mi = 0; mi < 4; mi++)
#pragma unroll
            for (int ni = 0; ni < 4; ni++) {
                int c = c0 + ni * 16 + cc;
#pragma unroll
                for (int j = 0; j < 4; j++)
                    C32[(size_t)(r0 + mi * 16 + cr + j) * DMODEL + c] = acc[mi][ni][j];
            }
    }
}

// ---------------- fused Q/K/V projection (LDS-staged) ----------------
__global__ __launch_bounds__(256) void proj3_kernel(const _Float16* __restrict__ Xh,
                                                    const _Float16* __restrict__ Wqh,
                                                    const _Float16* __restrict__ Wkh,
                                                    const _Float16* __restrict__ Wvh,
                                                    _Float16* __restrict__ Qh,
                                                    _Float16* __restrict__ Kh,
                                                    _Float16* __restrict__ Vt) {
    int z = blockIdx.z;
    const _Float16* B = (z == 0) ? Wqh : (z == 1) ? Wkh : Wvh;
    _Float16* C16 = (z == 0) ? Qh : (z == 1) ? Kh : Vt;
    gemm128_body(Xh, B, C16, nullptr, DMODEL,
                 blockIdx.y * 128, blockIdx.x * 128, z == 2 ? 1 : 0);
}

// ---------------- output projection (LDS-staged, fp32 C) ----------------
__global__ __launch_bounds__(256) void outgemm_kernel(const _Float16* __restrict__ A,
                                                      const _Float16* __restrict__ B,
                                                      float* __restrict__ C) {
    gemm128_body(A, B, nullptr, C, DMODEL, blockIdx.y * 128, blockIdx.x * 128, 2);
}

// ---------------- fused attention ----------------
// phase 1: K_STEP=128, shm = K-tile [128][66]
// phase 2: K_STEP=64,  shm = K [64][66] + V [64][66] (aliased)
__global__ __launch_bounds__(256) void attn_kernel(const _Float16* __restrict__ Q,
                                                   const _Float16* __restrict__ Kg,
                                                   const _Float16* __restrict__ Vg,
                                                   const float* __restrict__ lut,
                                                   const int* __restrict__ mask,
                                                   float* __restrict__ wts,
                                                   float* __restrict__ posb,
                                                   _Float16* __restrict__ attn0) {
    __shared__ _Float16 shm[128 * 66];
    __shared__ _Float16 Pl[4][16][72];
    int tid = threadIdx.x;
    int l = tid & 63, w = tid >> 6;
    int bid = blockIdx.x;               // 1024 blocks
    int xcd = bid & 7, idx = bid >> 3;
    int bh = (idx >> 5) * 8 + xcd;      // XCD-pinned K/V
    int qblk = idx & 31;
    int b = bh >> 4, h = bh & 15;
    int qbase = qblk * 64 + w * 16;
    size_t hoff = (size_t)(b * SEQ) * DMODEL + h * HEADD;
    int ar = l & 15, g = l >> 4, ak = g * 8;
    const float* luth = lut + h * LUTW;
    float* ob = wts + (size_t)bh * SEQ * SEQ;
    int q = qbase + ar;

    // phase-1 staging map: 128 rows x 64 cols, 64B/thread
    int sr1 = tid >> 1, sc1 = (tid & 1) * 32;
    const _Float16* K1src = Kg + hoff + sc1;
    // phase-2 staging map: 64 rows x 64 cols, 32B/thread (K) + 32B (V)
    int sr = tid >> 2, sc = (tid & 3) * 16;
    const _Float16* Ksrc = Kg + hoff + sc;
    const _Float16* Vsrc = Vg + ((size_t)bh * HEADD + sr) * SEQ + sc;

    half8 qf[2];
#pragma unroll
    for (int kk = 0; kk < 2; kk++)
        qf[kk] = *(const half8*)(Q + hoff + (size_t)q * DMODEL + kk * 32 + ak);

    // ---------- phase 1: online per-row stats (K_STEP = 128) ----------
    half8 s0 = *(const half8*)(K1src + (size_t)sr1 * DMODEL);
    half8 s1 = *(const half8*)(K1src + (size_t)sr1 * DMODEL + 8);
    half8 s2 = *(const half8*)(K1src + (size_t)sr1 * DMODEL + 16);
    half8 s3 = *(const half8*)(K1src + (size_t)sr1 * DMODEL + 24);
    float m = -3e38f, lsum = 0.f;
    for (int k0 = 0; k0 < SEQ; k0 += 128) {
        *(half8*)&shm[sr1 * 66 + sc1] = s0;
        *(half8*)&shm[sr1 * 66 + sc1 + 8] = s1;
        *(half8*)&shm[sr1 * 66 + sc1 + 16] = s2;
        *(half8*)&shm[sr1 * 66 + sc1 + 24] = s3;
        LDS_BAR();
        if (k0 + 128 < SEQ) {
            s0 = *(const half8*)(K1src + (size_t)(k0 + 128 + sr1) * DMODEL);
            s1 = *(const half8*)(K1src + (size_t)(k0 + 128 + sr1) * DMODEL + 8);
            s2 = *(const half8*)(K1src + (size_t)(k0 + 128 + sr1) * DMODEL + 16);
            s3 = *(const half8*)(K1src + (size_t)(k0 + 128 + sr1) * DMODEL + 24);
        }
        f32x4 acc[8];
#pragma unroll
        for (int ni = 0; ni < 8; ni++) {
            acc[ni] = f32x4{0.f, 0.f, 0.f, 0.f};
#pragma unroll
            for (int kk = 0; kk < 2; kk++) {
                half8 kf = *(const half8*)&shm[(ni * 16 + ar) * 66 + kk * 32 + ak];
                acc[ni] = __builtin_amdgcn_mfma_f32_16x16x32_f16(kf, qf[kk], acc[ni], 0, 0, 0);
            }
        }
        LDS_BAR();
        // two halves of 16 to cap live registers
        float hm[2], hs[2];
#pragma unroll
        for (int half = 0; half < 2; half++) {
            float vv[16];
#pragma unroll
            for (int ni = 0; ni < 4; ni++) {
                int nn = half * 4 + ni;
                int kcol = k0 + nn * 16 + g * 4;
                int4 mk = *(const int4*)(mask + b * SEQ + kcol);
                const int* mp = (const int*)&mk;
                f32x4 lb4;
                __builtin_memcpy(&lb4, luth + kcol - q + 2047, 16);
#pragma unroll
                for (int j = 0; j < 4; j++)
                    vv[ni * 4 + j] = mp[j] ? (acc[nn][j] + lb4[j]) : -1e9f;
            }
            float t8[8];
#pragma unroll
            for (int t = 0; t < 8; t++) t8[t] = fmaxf(vv[t], vv[t + 8]);
            float t4a = fmaxf(t8[0], t8[4]), t4b = fmaxf(t8[1], t8[5]);
            float t4c = fmaxf(t8[2], t8[6]), t4d = fmaxf(t8[3], t8[7]);
            float vmax = fmaxf(fmaxf(t4a, t4b), fmaxf(t4c, t4d));
            float p0 = 0.f, p1 = 0.f, p2 = 0.f, p3 = 0.f;
#pragma unroll
            for (int t = 0; t < 16; t += 4) {
                p0 += __expf(vv[t] - vmax);
                p1 += __expf(vv[t + 1] - vmax);
                p2 += __expf(vv[t + 2] - vmax);
                p3 += __expf(vv[t + 3] - vmax);
            }
            hm[half] = vmax;
            hs[half] = (p0 + p1) + (p2 + p3);
        }
        float mn = fmaxf(m, fmaxf(hm[0], hm[1]));
        lsum = lsum * __expf(m - mn) + hs[0] * __expf(hm[0] - mn) + hs[1] * __expf(hm[1] - mn);
        m = mn;
    }
    // prefetch phase-2 tile 0 (K and V) before the cross-lane reduction
    half8 t0 = *(const half8*)(Ksrc + (size_t)sr * DMODEL);
    half8 t1 = *(const half8*)(Ksrc + (size_t)sr * DMODEL + 8);
    half8 v0 = *(const half8*)(Vsrc);
    half8 v1 = *(const half8*)(Vsrc + 8);
#pragma unroll
    for (int off2 = 16; off2 <= 32; off2 <<= 1) {
        float mo = __shfl_xor(m, off2);
        float lo = __shfl_xor(lsum, off2);
        float mn = fmaxf(m, mo);
        lsum = lsum * __expf(m - mn) + lo * __expf(mo - mn);
        m = mn;
    }
    float invl = 1.0f / lsum;
    LDS_BAR();   // phase boundary: all waves done with phase-1 shm

    // ---------- phase 2: recompute -> weights (+posbias) + PV ----------
    _Float16* Kt2 = shm;                 // [64][66]
    _Float16* Vl2 = shm + 64 * 66;       // [64][66]
    f32x4 oacc[4] = {};
    for (int k0 = 0; k0 < SEQ; k0 += 64) {
        *(half8*)&Kt2[sr * 66 + sc] = t0;
        *(half8*)&Kt2[sr * 66 + sc + 8] = t1;
        *(half8*)&Vl2[sr * 66 + sc] = v0;
        *(half8*)&Vl2[sr * 66 + sc + 8] = v1;
        LDS_BAR();
        if (k0 + 64 < SEQ) {
            t0 = *(const half8*)(Ksrc + (size_t)(k0 + 64 + sr) * DMODEL);
            t1 = *(const half8*)(Ksrc + (size_t)(k0 + 64 + sr) * DMODEL + 8);
            v0 = *(const half8*)(Vsrc + k0 + 64);
            v1 = *(const half8*)(Vsrc + k0 + 64 + 8);
        }
        f32x4 acc[4] = {};
#pragma unroll
        for (int ni = 0; ni < 4; ni++)
#pragma unroll
            for (int kk = 0; kk < 2; kk++) {
                half8 kf = *(const half8*)&Kt2[(ni * 16 + ar) * 66 + kk * 32 + ak];
                acc[ni] = __builtin_amdgcn_mfma_f32_16x16x32_f16(kf, qf[kk], acc[ni], 0, 0, 0);
            }
        int pbsel = (k0 < SEQ / 2) ? 0 : 1;   // balance posbias stores across b
#pragma unroll
        for (int ni = 0; ni < 4; ni++) {
            int kcol = k0 + ni * 16 + g * 4;
            int4 mk = *(const int4*)(mask + b * SEQ + kcol);
            const int* mp = (const int*)&mk;
            f32x4 lb4;
            __builtin_memcpy(&lb4, luth + kcol - q + 2047, 16);
            f32x4 wv;
#pragma unroll
            for (int j = 0; j < 4; j++) {
                float v = mp[j] ? (acc[ni][j] + lb4[j]) : -1e9f;
                wv[j] = __expf(v - m) * invl;
            }
            nt_store_f4(ob + (size_t)q * SEQ + kcol, wv);
            if (b == pbsel)
                nt_store_f4(posb + (size_t)h * SEQ * SEQ + (size_t)q * SEQ + kcol, lb4);
            half4 ph;
#pragma unroll
            for (int j = 0; j < 4; j++) ph[j] = (_Float16)wv[j];
            *(half4*)&Pl[w][ar][ni * 16 + g * 4] = ph;
        }
        // PV: O[q,hd] += P[q,s] * V[s,hd]
#pragma unroll
        for (int kk2 = 0; kk2 < 2; kk2++) {
            half8 pa = *(half8*)&Pl[w][ar][kk2 * 32 + g * 8];
#pragma unroll
            for (int ni = 0; ni < 4; ni++) {
                half8 vf = *(const half8*)&Vl2[(ni * 16 + ar) * 66 + kk2 * 32 + g * 8];
                oacc[ni] = __builtin_amdgcn_mfma_f32_16x16x32_f16(pa, vf, oacc[ni], 0, 0, 0);
            }
        }
        LDS_BAR();
    }
#pragma unroll
    for (int ni = 0; ni < 4; ni++)
#pragma unroll
        for (int j = 0; j < 4; j++)
            attn0[(size_t)(b * SEQ + qbase + g * 4 + j) * DMODEL + h * HEADD + ni * 16 + ar] =
                (_Float16)oacc[ni][j];
}

extern "C" void kernel_launch(void* const* d_in, const int* in_sizes, int n_in,
                              void* d_out, int out_size, void* d_ws, size_t ws_size,
                              hipStream_t stream) {
    const float* hs = (const float*)d_in[0];
    const int* mask = (const int*)d_in[1];
    const float* Wq = (const float*)d_in[2];
    const float* Wk = (const float*)d_in[3];
    const float* Wv = (const float*)d_in[4];
    const float* Wo = (const float*)d_in[5];
    const float* rel_bias = (const float*)d_in[6];

    float* out_attn = (float*)d_out;                       // [2,2048,1024]
    float* out_wts = out_attn + (size_t)2 * SEQ * DMODEL;  // [2,16,2048,2048]
    float* out_posb = out_wts + (size_t)NBH * SEQ * SEQ;   // [1,16,2048,2048]

    char* ws = (char*)d_ws;
    size_t off = 0;
    auto carve = [&](size_t bytes) { void* p = ws + off; off += (bytes + 255) & ~(size_t)255; return p; };
    _Float16* Xh  = (_Float16*)carve((size_t)2 * SEQ * DMODEL * 2);
    _Float16* Wqh = (_Float16*)carve((size_t)DMODEL * DMODEL * 2);
    _Float16* Wkh = (_Float16*)carve((size_t)DMODEL * DMODEL * 2);
    _Float16* Wvh = (_Float16*)carve((size_t)DMODEL * DMODEL * 2);
    _Float16* Woh = (_Float16*)carve((size_t)DMODEL * DMODEL * 2);
    _Float16* Qh  = (_Float16*)carve((size_t)2 * SEQ * DMODEL * 2);
    _Float16* Kh  = (_Float16*)carve((size_t)2 * SEQ * DMODEL * 2);
    _Float16* Vt  = (_Float16*)carve((size_t)NBH * HEADD * SEQ * 2);
    _Float16* A0h = (_Float16*)carve((size_t)2 * SEQ * DMODEL * 2);
    float* lut    = (float*)carve((size_t)NHEAD * LUTW * 4);

    // 1. prep: casts + lut
    prep_kernel<<<4352, 256, 0, stream>>>(hs, Wq, Wk, Wv, Wo, rel_bias,
                                          Xh, Wqh, Wkh, Wvh, Woh, lut);

    // 2. Q/K/V projections (LDS-staged GEMM)
    dim3 pg(DMODEL / 128, (2 * SEQ) / 128, 3);
    proj3_kernel<<<pg, 256, 0, stream>>>(Xh, Wqh, Wkh, Wvh, Qh, Kh, Vt);

    // 3. fused attention
    attn_kernel<<<1024, 256, 0, stream>>>(Qh, Kh, Vt, lut, mask, out_wts, out_posb, A0h);

    // 4. output projection (LDS-staged GEMM)
    dim3 og(DMODEL / 128, (2 * SEQ) / 128);
    outgemm_kernel<<<og, 256, 0, stream>>>(A0h, Woh, out_attn);
}